// Round 5
// baseline (590.607 us; speedup 1.0000x reference)
//
#include <hip/hip_runtime.h>

// 2-layer LSTM, B=4096, T=168, D=16, H1=64, H2=32, fp32 in/out.
// R5: 512 thr/block, grid 256 (1 block/CU, 2 waves/SIMD), ping-pong LDS,
// 2 barriers/step. Wave roles:
//   w0-3 : L1 gates (32 MFMA, lo*lo dropped), x via direct global prefetch
//   w4,5 : L2 hi-part of W_ih2·h1 (16 MFMA) + partial combine + act + h2 write
//   w6,7 : L2 lo-cross of W_ih2·h1 + all W_hh2·h2 terms (20 MFMA) -> sP partials
// All weights register-resident (no per-step LDS weight reads).
// Matmul: mfma_f32_16x16x32_bf16, hi/lo bf16 split, lo*lo terms dropped
// (<=2^-18 relative -- negligible vs 1.7e-3 threshold).

typedef __bf16 bf16x8 __attribute__((ext_vector_type(8)));
typedef float  f32x4  __attribute__((ext_vector_type(4)));

constexpr int T_SEQ = 168;
constexpr int NB    = 16;

__device__ __forceinline__ float fsig(float v)  { return __builtin_amdgcn_rcpf(1.f + __expf(-v)); }
__device__ __forceinline__ float ftanhf(float v){ return 2.f * __builtin_amdgcn_rcpf(1.f + __expf(-2.f * v)) - 1.f; }

__device__ __forceinline__ void split_bf16(float x, __bf16& hi, __bf16& lo) {
  hi = (__bf16)x;
  lo = (__bf16)(x - (float)hi);
}

__device__ __forceinline__ void load_frag8(const float* __restrict__ Wrow, int k0,
                                           bf16x8& hi, bf16x8& lo) {
#pragma unroll
  for (int j = 0; j < 8; ++j) {
    float v = Wrow[k0 + j];
    __bf16 h = (__bf16)v;
    hi[j] = h;
    lo[j] = (__bf16)(v - (float)h);
  }
}

#define MFMA(a, b, c) __builtin_amdgcn_mfma_f32_16x16x32_bf16((a), (b), (c), 0, 0, 0)

__global__ __launch_bounds__(512, 1)
void lstm_mfma_kernel(const float* __restrict__ x,
    const float* __restrict__ Wih1, const float* __restrict__ Whh1,
    const float* __restrict__ bih1, const float* __restrict__ bhh1,
    const float* __restrict__ Wih2, const float* __restrict__ Whh2,
    const float* __restrict__ bih2, const float* __restrict__ bhh2,
    const float* __restrict__ Wfc,  const float* __restrict__ bfc,
    float* __restrict__ out)
{
  // A-fragment tiles, lane order [kb][lane][j], ping-pong buffered.
  __shared__ __align__(16) __bf16 sA1[2][4 * 64 * 8];   // h1 hi(kb0,1)/lo(kb2,3)
  __shared__ __align__(16) __bf16 sA2[2][2 * 64 * 8];   // h2 hi(kb0)/lo(kb1)
  __shared__ __align__(16) float  sP[2 * 4 * 64 * 4];   // L2 partial pre-acts [wl][g][lane][4]
  __shared__ __align__(16) float  sH2f[16 * 32];        // final h2 [batch][unit]

  const int tid  = threadIdx.x;
  const int w    = tid >> 6;        // wave 0..7
  const int lane = tid & 63;
  const int q    = lane >> 4;
  const int col  = lane & 15;
  const int b0   = blockIdx.x * NB;

  const bool isL1  = (w < 4);
  const bool isL2b = (w == 4) || (w == 5);  // hi-part + combine + act
  const bool isL2a = (w >= 6);              // lo-cross + hh2 -> partials
  const int  wl2b  = w - 4;
  const int  wl2a  = w - 6;

  // ---------------- weights into registers ----------------
  bf16x8 bhh[4][4];   // L1: W_hh1 hi(kb0,1)/lo(kb2,3)
  bf16x8 bih[4];      // L1: W_ih1 packed [Wh;Wl]
  float  b1v[4] = {0.f, 0.f, 0.f, 0.f};
  if (isL1) {
#pragma unroll
    for (int g = 0; g < 4; ++g) {
      const int r = g * 64 + w * 16 + col;
      const float* Wr = Whh1 + r * 64;
      bf16x8 h0, l0, h1f, l1f;
      load_frag8(Wr, 0 * 32 + q * 8, h0, l0);
      load_frag8(Wr, 1 * 32 + q * 8, h1f, l1f);
      bhh[g][0] = h0; bhh[g][1] = h1f; bhh[g][2] = l0; bhh[g][3] = l1f;
      bf16x8 xh, xl;
      load_frag8(Wih1 + r * 16, (q & 1) * 8, xh, xl);
      bih[g] = (q < 2) ? xh : xl;
      b1v[g] = bih1[r] + bhh1[r];
    }
  }
  bf16x8 w2h_[4][2], w2l_[4][2];  // L2b: W_ih2 hi/lo, k-blocks 0,1
  float  b2v[4] = {0.f, 0.f, 0.f, 0.f};
  if (isL2b) {
#pragma unroll
    for (int g = 0; g < 4; ++g) {
      const int r = g * 32 + wl2b * 16 + col;
#pragma unroll
      for (int kb = 0; kb < 2; ++kb) {
        bf16x8 hh, ll;
        load_frag8(Wih2 + r * 64, kb * 32 + q * 8, hh, ll);
        w2h_[g][kb] = hh; w2l_[g][kb] = ll;
      }
      b2v[g] = bih2[r] + bhh2[r];
    }
  }
  bf16x8 w2a[4][2];               // L2a: W_ih2 hi (for lo-cross terms)
  bf16x8 bh2h[4], bh2l[4];        // L2a: W_hh2 hi/lo
  if (isL2a) {
#pragma unroll
    for (int g = 0; g < 4; ++g) {
      const int r = g * 32 + wl2a * 16 + col;
#pragma unroll
      for (int kb = 0; kb < 2; ++kb) {
        bf16x8 hh, ll;
        load_frag8(Wih2 + r * 64, kb * 32 + q * 8, hh, ll);
        w2a[g][kb] = hh;
      }
      bf16x8 hh, ll;
      load_frag8(Whh2 + r * 32, q * 8, hh, ll);
      bh2h[g] = hh; bh2l[g] = ll;
    }
  }

  // ---------------- zero state buffers ----------------
  {
    bf16x8 z;
#pragma unroll
    for (int j = 0; j < 8; ++j) z[j] = (__bf16)0.f;
    for (int i = tid; i < 2 * 4 * 64; i += 512) *(bf16x8*)&sA1[0][i * 8] = z;
    for (int i = tid; i < 2 * 2 * 64; i += 512) *(bf16x8*)&sA2[0][i * 8] = z;
  }
  __syncthreads();

  // x prefetch registers (L1 waves; lane (col,q) owns x[b0+col][t][(q&1)*8 .. +8])
  const float* xbase = x + ((size_t)(b0 + col) * T_SEQ) * 16 + (q & 1) * 8;
  float4 xcA, xcB, xnA, xnB;
  if (isL1) {
    xcA = *(const float4*)(xbase + 0);
    xcB = *(const float4*)(xbase + 4);
  }

  float c1s[4] = {0.f, 0.f, 0.f, 0.f};
  float c2s[4] = {0.f, 0.f, 0.f, 0.f};
  const int uu   = w * 16 + col;      // L1 unit
  const int uu2b = wl2b * 16 + col;   // L2b unit

  for (int t = 0; t <= T_SEQ; ++t) {
    const int p = t & 1;

    // ================= section 1 =================
    if (isL1 && t + 1 < T_SEQ) {   // issue next-x loads (consumed next step)
      const float* xr = xbase + (size_t)(t + 1) * 16;
      xnA = *(const float4*)(xr + 0);
      xnB = *(const float4*)(xr + 4);
    }

    if (isL2a && t >= 1) {         // lo-cross + hh2 partials
      const bf16x8 a2l0 = *(const bf16x8*)&sA1[p][(2 * 64 + lane) * 8];
      const bf16x8 a2l1 = *(const bf16x8*)&sA1[p][(3 * 64 + lane) * 8];
      const bf16x8 ah0  = *(const bf16x8*)&sA2[p][(0 * 64 + lane) * 8];
      const bf16x8 ah1  = *(const bf16x8*)&sA2[p][(1 * 64 + lane) * 8];
#pragma unroll
      for (int g = 0; g < 4; ++g) {
        f32x4 pa = {0.f, 0.f, 0.f, 0.f};
        pa = MFMA(a2l0, w2a[g][0], pa);   // h1lo x Wih2hi
        pa = MFMA(a2l1, w2a[g][1], pa);
        pa = MFMA(ah0,  bh2h[g],  pa);    // h2hi x Whh2hi
        pa = MFMA(ah1,  bh2h[g],  pa);    // h2lo x Whh2hi
        pa = MFMA(ah0,  bh2l[g],  pa);    // h2hi x Whh2lo
        *(f32x4*)&sP[((wl2a * 4 + g) * 64 + lane) * 4] = pa;
      }
    }

    f32x4 c2[4];
    if (isL2b && t >= 1) {         // hi-part of W_ih2 . h1
      const bf16x8 a2h0 = *(const bf16x8*)&sA1[p][(0 * 64 + lane) * 8];
      const bf16x8 a2h1 = *(const bf16x8*)&sA1[p][(1 * 64 + lane) * 8];
#pragma unroll
      for (int g = 0; g < 4; ++g) {
        c2[g][0] = b2v[g]; c2[g][1] = b2v[g]; c2[g][2] = b2v[g]; c2[g][3] = b2v[g];
        c2[g] = MFMA(a2h0, w2h_[g][0], c2[g]);  // hi x hi
        c2[g] = MFMA(a2h1, w2h_[g][1], c2[g]);
        c2[g] = MFMA(a2h0, w2l_[g][0], c2[g]);  // hi x lo
        c2[g] = MFMA(a2h1, w2l_[g][1], c2[g]);
      }
    }
    __syncthreads();   // mid: sP published; section-1 reads of buf p complete

    // ================= section 2 =================
    if (isL1 && t < T_SEQ) {
      // x fragments from prefetched registers
      const float xc[8] = {xcA.x, xcA.y, xcA.z, xcA.w, xcB.x, xcB.y, xcB.z, xcB.w};
      bf16x8 xh8, xl8;
#pragma unroll
      for (int j = 0; j < 8; ++j) {
        __bf16 h, l; split_bf16(xc[j], h, l);
        xh8[j] = h; xl8[j] = l;
      }
      const bf16x8 ax0 = (q < 2) ? xh8 : xl8;
      const bf16x8 ax1 = (q < 2) ? xl8 : xh8;

      bf16x8 a1[4];
#pragma unroll
      for (int kb = 0; kb < 4; ++kb) a1[kb] = *(const bf16x8*)&sA1[p][(kb * 64 + lane) * 8];

      f32x4 c[4];
#pragma unroll
      for (int g = 0; g < 4; ++g) { c[g][0] = b1v[g]; c[g][1] = b1v[g]; c[g][2] = b1v[g]; c[g][3] = b1v[g]; }
#pragma unroll
      for (int g = 0; g < 4; ++g) {
        c[g] = MFMA(ax0,   bih[g],    c[g]);
        c[g] = MFMA(ax1,   bih[g],    c[g]);
        c[g] = MFMA(a1[0], bhh[g][0], c[g]);  // hi x hi
        c[g] = MFMA(a1[1], bhh[g][1], c[g]);
        c[g] = MFMA(a1[2], bhh[g][0], c[g]);  // lo x hi
        c[g] = MFMA(a1[3], bhh[g][1], c[g]);
        c[g] = MFMA(a1[0], bhh[g][2], c[g]);  // hi x lo
        c[g] = MFMA(a1[1], bhh[g][3], c[g]);
      }
      const int kbh = uu >> 5;
      const int lnb = ((uu & 31) >> 3) * 16;
      const int jj  = uu & 7;
#pragma unroll
      for (int r = 0; r < 4; ++r) {
        const float iv = fsig(c[0][r]);
        const float fv = fsig(c[1][r]);
        const float gv = ftanhf(c[2][r]);
        const float ov = fsig(c[3][r]);
        const float cc = fmaf(fv, c1s[r], iv * gv);
        c1s[r] = cc;
        __bf16 hh, hl;
        split_bf16(ov * ftanhf(cc), hh, hl);
        const int m = q * 4 + r;
        sA1[1 - p][((kbh * 64) + lnb + m) * 8 + jj]       = hh;
        sA1[1 - p][(((2 + kbh) * 64) + lnb + m) * 8 + jj] = hl;
      }
      xcA = xnA; xcB = xnB;   // rotate prefetch
    }

    if (isL2b && t >= 1) {
      const int lnb2 = ((uu2b & 31) >> 3) * 16;
      const int jj2  = uu2b & 7;
#pragma unroll
      for (int g = 0; g < 4; ++g)
        c2[g] += *(const f32x4*)&sP[((wl2b * 4 + g) * 64 + lane) * 4];
#pragma unroll
      for (int r = 0; r < 4; ++r) {
        const float iv = fsig(c2[0][r]);
        const float fv = fsig(c2[1][r]);
        const float gv = ftanhf(c2[2][r]);
        const float ov = fsig(c2[3][r]);
        const float cc = fmaf(fv, c2s[r], iv * gv);
        c2s[r] = cc;
        const float hf = ov * ftanhf(cc);
        __bf16 hh, hl;
        split_bf16(hf, hh, hl);
        const int m = q * 4 + r;
        sA2[1 - p][((0 * 64) + lnb2 + m) * 8 + jj2] = hh;
        sA2[1 - p][((1 * 64) + lnb2 + m) * 8 + jj2] = hl;
        if (t == T_SEQ) sH2f[m * 32 + uu2b] = hf;
      }
    }
    __syncthreads();   // end: buf 1-p fully written
  }

  // ======== FC epilogue ========
  if (tid < NB) {
    float s = bfc[0];
#pragma unroll
    for (int j = 0; j < 32; ++j) s = fmaf(Wfc[j], sH2f[tid * 32 + j], s);
    out[b0 + tid] = s;
  }
}

extern "C" void kernel_launch(void* const* d_in, const int* in_sizes, int n_in,
                              void* d_out, int out_size, void* d_ws, size_t ws_size,
                              hipStream_t stream) {
  (void)in_sizes; (void)n_in; (void)out_size; (void)d_ws; (void)ws_size;
  const float* x    = (const float*)d_in[0];
  const float* Wih1 = (const float*)d_in[1];
  const float* Whh1 = (const float*)d_in[2];
  const float* bih1 = (const float*)d_in[3];
  const float* bhh1 = (const float*)d_in[4];
  const float* Wih2 = (const float*)d_in[5];
  const float* Whh2 = (const float*)d_in[6];
  const float* bih2 = (const float*)d_in[7];
  const float* bhh2 = (const float*)d_in[8];
  const float* Wfc  = (const float*)d_in[9];
  const float* bfc  = (const float*)d_in[10];
  float* out = (float*)d_out;

  hipLaunchKernelGGL(lstm_mfma_kernel, dim3(4096 / NB), dim3(512), 0, stream,
                     x, Wih1, Whh1, bih1, bhh1, Wih2, Whh2, bih2, bhh2, Wfc, bfc, out);
}

// Round 6
// 328.166 us; speedup vs baseline: 1.7997x; 1.7997x over previous
//
#include <hip/hip_runtime.h>

// 2-layer LSTM, B=4096, T=168, D=16, H1=64, H2=32, fp32 in/out.
// R6: R5's wave-split pipeline with ALL layer-2 weights in LDS (R5's
// register-resident L2 weights created a ~200-VGPR union across wave roles
// -> spills -> 55 MB scratch writes). Roles (512 thr, grid 256, 1 block/CU):
//   w0-3 : L1 gates (32 MFMA, lo*lo dropped), x prefetched into registers
//   w4,5 : L2 hi-part of W_ih2.h1 (16 MFMA, weights from LDS) + combine + act
//   w6,7 : L2 lo-cross of W_ih2.h1 + all W_hh2.h2 (20 MFMA, weights from LDS)
// Ping-pong state buffers, 2 barriers/step. mfma_f32_16x16x32_bf16 hi/lo
// split, lo*lo dropped (~2^-18 relative, validated in R5: absmax 6.1e-5).

typedef __bf16 bf16x8 __attribute__((ext_vector_type(8)));
typedef float  f32x4  __attribute__((ext_vector_type(4)));

constexpr int T_SEQ = 168;
constexpr int NB    = 16;

__device__ __forceinline__ float fsig(float v)  { return __builtin_amdgcn_rcpf(1.f + __expf(-v)); }
__device__ __forceinline__ float ftanhf(float v){ return 2.f * __builtin_amdgcn_rcpf(1.f + __expf(-2.f * v)) - 1.f; }

__device__ __forceinline__ void split_bf16(float x, __bf16& hi, __bf16& lo) {
  hi = (__bf16)x;
  lo = (__bf16)(x - (float)hi);
}

__device__ __forceinline__ void load_frag8(const float* __restrict__ Wrow, int k0,
                                           bf16x8& hi, bf16x8& lo) {
#pragma unroll
  for (int j = 0; j < 8; ++j) {
    float v = Wrow[k0 + j];
    __bf16 h = (__bf16)v;
    hi[j] = h;
    lo[j] = (__bf16)(v - (float)h);
  }
}

#define MFMA(a, b, c) __builtin_amdgcn_mfma_f32_16x16x32_bf16((a), (b), (c), 0, 0, 0)

__global__ __launch_bounds__(512, 1)
void lstm_mfma_kernel(const float* __restrict__ x,
    const float* __restrict__ Wih1, const float* __restrict__ Whh1,
    const float* __restrict__ bih1, const float* __restrict__ bhh1,
    const float* __restrict__ Wih2, const float* __restrict__ Whh2,
    const float* __restrict__ bih2, const float* __restrict__ bhh2,
    const float* __restrict__ Wfc,  const float* __restrict__ bfc,
    float* __restrict__ out)
{
  __shared__ __align__(16) __bf16 sA1[2][4 * 64 * 8];    // h1 hi(kb0,1)/lo(kb2,3)
  __shared__ __align__(16) __bf16 sA2[2][2 * 64 * 8];    // h2 hi(kb0)/lo(kb1)
  __shared__ __align__(16) __bf16 sW2[8 * 4 * 64 * 8];   // W_ih2 frags [nt=g*2+wl][kb][lane], kb<2 hi, kb>=2 lo (32 KB)
  __shared__ __align__(16) __bf16 sWh2[2 * 4 * 2 * 64 * 8]; // W_hh2 frags [(wl*4+g)*2+hl][lane] (16 KB)
  __shared__ __align__(16) float  sP[2 * 4 * 64 * 4];    // L2 partial pre-acts [wl][g][lane][4]
  __shared__ __align__(16) float  sH2f[16 * 32];         // final h2 [batch][unit]

  const int tid  = threadIdx.x;
  const int w    = tid >> 6;        // wave 0..7
  const int lane = tid & 63;
  const int q    = lane >> 4;
  const int col  = lane & 15;
  const int b0   = blockIdx.x * NB;

  const bool isL1  = (w < 4);
  const bool isL2b = (w == 4) || (w == 5);  // hi-part + combine + act + h2 write
  const bool isL2a = (w >= 6);              // lo-cross + hh2 -> partials
  const int  wl2b  = w - 4;
  const int  wl2a  = w - 6;

  // ---------------- L1 weights into registers (only role with reg weights) ----------------
  bf16x8 bhh[4][4];   // W_hh1 hi(kb0,1)/lo(kb2,3)
  bf16x8 bih[4];      // W_ih1 packed [Wh;Wl]
  float  b1v[4] = {0.f, 0.f, 0.f, 0.f};
  if (isL1) {
#pragma unroll
    for (int g = 0; g < 4; ++g) {
      const int r = g * 64 + w * 16 + col;
      const float* Wr = Whh1 + r * 64;
      bf16x8 h0, l0, h1f, l1f;
      load_frag8(Wr, 0 * 32 + q * 8, h0, l0);
      load_frag8(Wr, 1 * 32 + q * 8, h1f, l1f);
      bhh[g][0] = h0; bhh[g][1] = h1f; bhh[g][2] = l0; bhh[g][3] = l1f;
      bf16x8 xh, xl;
      load_frag8(Wih1 + r * 16, (q & 1) * 8, xh, xl);
      bih[g] = (q < 2) ? xh : xl;
      b1v[g] = bih1[r] + bhh1[r];
    }
  }
  float b2v[4] = {0.f, 0.f, 0.f, 0.f};
  if (isL2b) {
#pragma unroll
    for (int g = 0; g < 4; ++g) {
      const int r = g * 32 + wl2b * 16 + col;
      b2v[g] = bih2[r] + bhh2[r];
    }
  }

  // ---------------- LDS staging: W_ih2 B-frags (R4-proven layout) ----------------
  for (int idx = tid; idx < 8 * 4 * 64; idx += 512) {
    const int nt = idx >> 8;          // nt = g*2 + wl
    const int kb = (idx >> 6) & 3;
    const int ln = idx & 63;
    const int qq = ln >> 4, cc = ln & 15;
    const int g  = nt >> 1, wv = nt & 1;
    const int r  = g * 32 + wv * 16 + cc;
    const int k0 = (kb & 1) * 32 + qq * 8;
    bf16x8 hh, ll;
    load_frag8(Wih2 + r * 64, k0, hh, ll);
    *(bf16x8*)&sW2[((nt * 4 + kb) * 64 + ln) * 8] = (kb < 2) ? hh : ll;
  }
  // ---------------- LDS staging: W_hh2 B-frags ----------------
  for (int idx = tid; idx < 2 * 4 * 2 * 64; idx += 512) {
    const int ln = idx & 63;
    const int hl = (idx >> 6) & 1;
    const int g  = (idx >> 7) & 3;
    const int wl = idx >> 9;
    const int qq = ln >> 4, cc = ln & 15;
    const int r  = g * 32 + wl * 16 + cc;
    bf16x8 hh, ll;
    load_frag8(Whh2 + r * 32, qq * 8, hh, ll);
    *(bf16x8*)&sWh2[(((wl * 4 + g) * 2 + hl) * 64 + ln) * 8] = hl ? ll : hh;
  }

  // ---------------- zero state buffers ----------------
  {
    bf16x8 z;
#pragma unroll
    for (int j = 0; j < 8; ++j) z[j] = (__bf16)0.f;
    for (int i = tid; i < 2 * 4 * 64; i += 512) *(bf16x8*)&sA1[0][i * 8] = z;
    for (int i = tid; i < 2 * 2 * 64; i += 512) *(bf16x8*)&sA2[0][i * 8] = z;
  }
  __syncthreads();

  // x prefetch registers (L1 waves; lane (col,q) owns x[b0+col][t][(q&1)*8 .. +8])
  const float* xbase = x + ((size_t)(b0 + col) * T_SEQ) * 16 + (q & 1) * 8;
  float4 xcA, xcB, xnA, xnB;
  if (isL1) {
    xcA = *(const float4*)(xbase + 0);
    xcB = *(const float4*)(xbase + 4);
  }

  float c1s[4] = {0.f, 0.f, 0.f, 0.f};
  float c2s[4] = {0.f, 0.f, 0.f, 0.f};
  const int uu   = w * 16 + col;      // L1 unit
  const int uu2b = wl2b * 16 + col;   // L2b unit

  for (int t = 0; t <= T_SEQ; ++t) {
    const int p = t & 1;

    // ================= section 1 =================
    if (isL1 && t + 1 < T_SEQ) {   // issue next-x loads early
      const float* xr = xbase + (size_t)(t + 1) * 16;
      xnA = *(const float4*)(xr + 0);
      xnB = *(const float4*)(xr + 4);
    }

    if (isL2a && t >= 1) {         // lo-cross + hh2 -> partials (weights from LDS)
      const bf16x8 a2l0 = *(const bf16x8*)&sA1[p][(2 * 64 + lane) * 8];
      const bf16x8 a2l1 = *(const bf16x8*)&sA1[p][(3 * 64 + lane) * 8];
      const bf16x8 ah0  = *(const bf16x8*)&sA2[p][(0 * 64 + lane) * 8];
      const bf16x8 ah1  = *(const bf16x8*)&sA2[p][(1 * 64 + lane) * 8];
#pragma unroll
      for (int g = 0; g < 4; ++g) {
        const int nt = g * 2 + wl2a;
        const bf16x8 whi0 = *(const bf16x8*)&sW2[((nt * 4 + 0) * 64 + lane) * 8];
        const bf16x8 whi1 = *(const bf16x8*)&sW2[((nt * 4 + 1) * 64 + lane) * 8];
        const bf16x8 whh  = *(const bf16x8*)&sWh2[(((wl2a * 4 + g) * 2 + 0) * 64 + lane) * 8];
        const bf16x8 whl  = *(const bf16x8*)&sWh2[(((wl2a * 4 + g) * 2 + 1) * 64 + lane) * 8];
        f32x4 pa = {0.f, 0.f, 0.f, 0.f};
        pa = MFMA(a2l0, whi0, pa);   // h1lo x Wih2hi
        pa = MFMA(a2l1, whi1, pa);
        pa = MFMA(ah0,  whh,  pa);   // h2hi x Whh2hi
        pa = MFMA(ah1,  whh,  pa);   // h2lo x Whh2hi
        pa = MFMA(ah0,  whl,  pa);   // h2hi x Whh2lo
        *(f32x4*)&sP[((wl2a * 4 + g) * 64 + lane) * 4] = pa;
      }
    }

    f32x4 c2[4];
    if (isL2b && t >= 1) {         // hi-part of W_ih2 . h1 (weights from LDS)
      const bf16x8 a2h0 = *(const bf16x8*)&sA1[p][(0 * 64 + lane) * 8];
      const bf16x8 a2h1 = *(const bf16x8*)&sA1[p][(1 * 64 + lane) * 8];
#pragma unroll
      for (int g = 0; g < 4; ++g) {
        const int nt = g * 2 + wl2b;
        const bf16x8 bb0 = *(const bf16x8*)&sW2[((nt * 4 + 0) * 64 + lane) * 8];
        const bf16x8 bb1 = *(const bf16x8*)&sW2[((nt * 4 + 1) * 64 + lane) * 8];
        const bf16x8 bb2 = *(const bf16x8*)&sW2[((nt * 4 + 2) * 64 + lane) * 8];
        const bf16x8 bb3 = *(const bf16x8*)&sW2[((nt * 4 + 3) * 64 + lane) * 8];
        c2[g][0] = b2v[g]; c2[g][1] = b2v[g]; c2[g][2] = b2v[g]; c2[g][3] = b2v[g];
        c2[g] = MFMA(a2h0, bb0, c2[g]);  // hi x hi
        c2[g] = MFMA(a2h1, bb1, c2[g]);
        c2[g] = MFMA(a2h0, bb2, c2[g]);  // hi x lo
        c2[g] = MFMA(a2h1, bb3, c2[g]);
      }
    }
    __syncthreads();   // mid: sP published; section-1 reads of buf p complete

    // ================= section 2 =================
    if (isL1 && t < T_SEQ) {
      const float xc[8] = {xcA.x, xcA.y, xcA.z, xcA.w, xcB.x, xcB.y, xcB.z, xcB.w};
      bf16x8 xh8, xl8;
#pragma unroll
      for (int j = 0; j < 8; ++j) {
        __bf16 h, l; split_bf16(xc[j], h, l);
        xh8[j] = h; xl8[j] = l;
      }
      const bf16x8 ax0 = (q < 2) ? xh8 : xl8;
      const bf16x8 ax1 = (q < 2) ? xl8 : xh8;

      bf16x8 a1[4];
#pragma unroll
      for (int kb = 0; kb < 4; ++kb) a1[kb] = *(const bf16x8*)&sA1[p][(kb * 64 + lane) * 8];

      f32x4 c[4];
#pragma unroll
      for (int g = 0; g < 4; ++g) { c[g][0] = b1v[g]; c[g][1] = b1v[g]; c[g][2] = b1v[g]; c[g][3] = b1v[g]; }
#pragma unroll
      for (int g = 0; g < 4; ++g) {
        c[g] = MFMA(ax0,   bih[g],    c[g]);
        c[g] = MFMA(ax1,   bih[g],    c[g]);
        c[g] = MFMA(a1[0], bhh[g][0], c[g]);  // hi x hi
        c[g] = MFMA(a1[1], bhh[g][1], c[g]);
        c[g] = MFMA(a1[2], bhh[g][0], c[g]);  // lo x hi
        c[g] = MFMA(a1[3], bhh[g][1], c[g]);
        c[g] = MFMA(a1[0], bhh[g][2], c[g]);  // hi x lo
        c[g] = MFMA(a1[1], bhh[g][3], c[g]);
      }
      const int kbh = uu >> 5;
      const int lnb = ((uu & 31) >> 3) * 16;
      const int jj  = uu & 7;
#pragma unroll
      for (int r = 0; r < 4; ++r) {
        const float iv = fsig(c[0][r]);
        const float fv = fsig(c[1][r]);
        const float gv = ftanhf(c[2][r]);
        const float ov = fsig(c[3][r]);
        const float cc = fmaf(fv, c1s[r], iv * gv);
        c1s[r] = cc;
        __bf16 hh, hl;
        split_bf16(ov * ftanhf(cc), hh, hl);
        const int m = q * 4 + r;
        sA1[1 - p][((kbh * 64) + lnb + m) * 8 + jj]       = hh;
        sA1[1 - p][(((2 + kbh) * 64) + lnb + m) * 8 + jj] = hl;
      }
      xcA = xnA; xcB = xnB;   // rotate prefetch
    }

    if (isL2b && t >= 1) {
      const int lnb2 = ((uu2b & 31) >> 3) * 16;
      const int jj2  = uu2b & 7;
#pragma unroll
      for (int g = 0; g < 4; ++g)
        c2[g] += *(const f32x4*)&sP[((wl2b * 4 + g) * 64 + lane) * 4];
#pragma unroll
      for (int r = 0; r < 4; ++r) {
        const float iv = fsig(c2[0][r]);
        const float fv = fsig(c2[1][r]);
        const float gv = ftanhf(c2[2][r]);
        const float ov = fsig(c2[3][r]);
        const float cc = fmaf(fv, c2s[r], iv * gv);
        c2s[r] = cc;
        const float hf = ov * ftanhf(cc);
        __bf16 hh, hl;
        split_bf16(hf, hh, hl);
        const int m = q * 4 + r;
        sA2[1 - p][((0 * 64) + lnb2 + m) * 8 + jj2] = hh;
        sA2[1 - p][((1 * 64) + lnb2 + m) * 8 + jj2] = hl;
        if (t == T_SEQ) sH2f[m * 32 + uu2b] = hf;
      }
    }
    __syncthreads();   // end: buf 1-p fully written
  }

  // ======== FC epilogue ========
  if (tid < NB) {
    float s = bfc[0];
#pragma unroll
    for (int j = 0; j < 32; ++j) s = fmaf(Wfc[j], sH2f[tid * 32 + j], s);
    out[b0 + tid] = s;
  }
}

extern "C" void kernel_launch(void* const* d_in, const int* in_sizes, int n_in,
                              void* d_out, int out_size, void* d_ws, size_t ws_size,
                              hipStream_t stream) {
  (void)in_sizes; (void)n_in; (void)out_size; (void)d_ws; (void)ws_size;
  const float* x    = (const float*)d_in[0];
  const float* Wih1 = (const float*)d_in[1];
  const float* Whh1 = (const float*)d_in[2];
  const float* bih1 = (const float*)d_in[3];
  const float* bhh1 = (const float*)d_in[4];
  const float* Wih2 = (const float*)d_in[5];
  const float* Whh2 = (const float*)d_in[6];
  const float* bih2 = (const float*)d_in[7];
  const float* bhh2 = (const float*)d_in[8];
  const float* Wfc  = (const float*)d_in[9];
  const float* bfc  = (const float*)d_in[10];
  float* out = (float*)d_out;

  hipLaunchKernelGGL(lstm_mfma_kernel, dim3(4096 / NB), dim3(512), 0, stream,
                     x, Wih1, Whh1, bih1, bhh1, Wih2, Whh2, bih2, bhh2, Wfc, bfc, out);
}

// Round 7
// 292.729 us; speedup vs baseline: 2.0176x; 1.1211x over previous
//
#include <hip/hip_runtime.h>

// 2-layer LSTM, B=4096, T=168, D=16, H1=64, H2=32, fp32 in/out.
// R7: fully software-pipelined wave specialization, ONE barrier per interval
// (R6's mid-barrier serialized L2a -> L1; here every dependency crosses
// exactly one end-of-interval barrier). 512 thr/block, grid 256 (1 block/CU).
// Interval t:
//   w0-3 : h1(t)   = LSTM1(h1(t-1), x(t))            [32 MFMA, lo*lo dropped]
//   w6,7 : pA(t-1) = full W_ih2 . h1(t-1)            [24 MFMA, weights in LDS]
//   w4,5 : h2(t-2) = act(pA(t-2) + W_hh2 . h2(t-3))  [12 MFMA, self-recurrent]
// Ping-pong sA1/sA2/sP; loop t=0..T+1 (2-interval drain).
// mfma_f32_16x16x32_bf16 hi/lo split, lo*lo dropped (validated: absmax 6.1e-5).

typedef __bf16 bf16x8 __attribute__((ext_vector_type(8)));
typedef float  f32x4  __attribute__((ext_vector_type(4)));

constexpr int T_SEQ = 168;
constexpr int NB    = 16;

__device__ __forceinline__ float fsig(float v)  { return __builtin_amdgcn_rcpf(1.f + __expf(-v)); }
__device__ __forceinline__ float ftanhf(float v){ return 2.f * __builtin_amdgcn_rcpf(1.f + __expf(-2.f * v)) - 1.f; }

__device__ __forceinline__ void split_bf16(float x, __bf16& hi, __bf16& lo) {
  hi = (__bf16)x;
  lo = (__bf16)(x - (float)hi);
}

__device__ __forceinline__ void load_frag8(const float* __restrict__ Wrow, int k0,
                                           bf16x8& hi, bf16x8& lo) {
#pragma unroll
  for (int j = 0; j < 8; ++j) {
    float v = Wrow[k0 + j];
    __bf16 h = (__bf16)v;
    hi[j] = h;
    lo[j] = (__bf16)(v - (float)h);
  }
}

#define MFMA(a, b, c) __builtin_amdgcn_mfma_f32_16x16x32_bf16((a), (b), (c), 0, 0, 0)

__global__ __launch_bounds__(512, 1)
void lstm_mfma_kernel(const float* __restrict__ x,
    const float* __restrict__ Wih1, const float* __restrict__ Whh1,
    const float* __restrict__ bih1, const float* __restrict__ bhh1,
    const float* __restrict__ Wih2, const float* __restrict__ Whh2,
    const float* __restrict__ bih2, const float* __restrict__ bhh2,
    const float* __restrict__ Wfc,  const float* __restrict__ bfc,
    float* __restrict__ out)
{
  __shared__ __align__(16) __bf16 sA1[2][4 * 64 * 8];      // h1 hi(kb0,1)/lo(kb2,3)
  __shared__ __align__(16) __bf16 sA2[2][2 * 64 * 8];      // h2 hi(kb0)/lo(kb1)
  __shared__ __align__(16) __bf16 sW2[8 * 4 * 64 * 8];     // W_ih2 frags [nt=g*2+wl][kb][lane] (32 KB)
  __shared__ __align__(16) __bf16 sWh2[2 * 4 * 2 * 64 * 8];// W_hh2 frags [(wl*4+g)*2+hl][lane] (16 KB)
  __shared__ __align__(16) float  sP[2][2 * 4 * 64 * 4];   // pA partials, ping-pong (16 KB)
  __shared__ __align__(16) float  sH2f[16 * 32];           // final h2 [batch][unit]

  const int tid  = threadIdx.x;
  const int w    = tid >> 6;        // wave 0..7
  const int lane = tid & 63;
  const int q    = lane >> 4;
  const int col  = lane & 15;
  const int b0   = blockIdx.x * NB;

  const bool isL1  = (w < 4);
  const bool isL2b = (w == 4) || (w == 5);  // combine + hh2 + act + h2 write
  const bool isL2a = (w >= 6);              // full W_ih2 . h1 -> partials
  const int  wl2b  = w - 4;
  const int  wl2a  = w - 6;

  // ---------------- L1 weights into registers (only role with reg weights) ----------------
  bf16x8 bhh[4][4];   // W_hh1 hi(kb0,1)/lo(kb2,3)
  bf16x8 bih[4];      // W_ih1 packed [Wh;Wl]
  float  b1v[4] = {0.f, 0.f, 0.f, 0.f};
  if (isL1) {
#pragma unroll
    for (int g = 0; g < 4; ++g) {
      const int r = g * 64 + w * 16 + col;
      const float* Wr = Whh1 + r * 64;
      bf16x8 h0, l0, h1f, l1f;
      load_frag8(Wr, 0 * 32 + q * 8, h0, l0);
      load_frag8(Wr, 1 * 32 + q * 8, h1f, l1f);
      bhh[g][0] = h0; bhh[g][1] = h1f; bhh[g][2] = l0; bhh[g][3] = l1f;
      bf16x8 xh, xl;
      load_frag8(Wih1 + r * 16, (q & 1) * 8, xh, xl);
      bih[g] = (q < 2) ? xh : xl;
      b1v[g] = bih1[r] + bhh1[r];
    }
  }
  float b2v[4] = {0.f, 0.f, 0.f, 0.f};
  if (isL2b) {
#pragma unroll
    for (int g = 0; g < 4; ++g) {
      const int r = g * 32 + wl2b * 16 + col;
      b2v[g] = bih2[r] + bhh2[r];
    }
  }

  // ---------------- LDS staging: W_ih2 B-frags ----------------
  for (int idx = tid; idx < 8 * 4 * 64; idx += 512) {
    const int nt = idx >> 8;          // nt = g*2 + wl
    const int kb = (idx >> 6) & 3;
    const int ln = idx & 63;
    const int qq = ln >> 4, cc = ln & 15;
    const int g  = nt >> 1, wv = nt & 1;
    const int r  = g * 32 + wv * 16 + cc;
    const int k0 = (kb & 1) * 32 + qq * 8;
    bf16x8 hh, ll;
    load_frag8(Wih2 + r * 64, k0, hh, ll);
    *(bf16x8*)&sW2[((nt * 4 + kb) * 64 + ln) * 8] = (kb < 2) ? hh : ll;
  }
  // ---------------- LDS staging: W_hh2 B-frags ----------------
  for (int idx = tid; idx < 2 * 4 * 2 * 64; idx += 512) {
    const int ln = idx & 63;
    const int hl = (idx >> 6) & 1;
    const int g  = (idx >> 7) & 3;
    const int wl = idx >> 9;
    const int qq = ln >> 4, cc = ln & 15;
    const int r  = g * 32 + wl * 16 + cc;
    bf16x8 hh, ll;
    load_frag8(Whh2 + r * 32, qq * 8, hh, ll);
    *(bf16x8*)&sWh2[(((wl * 4 + g) * 2 + hl) * 64 + ln) * 8] = hl ? ll : hh;
  }

  // ---------------- zero state buffers (both ping-pong halves) ----------------
  {
    bf16x8 z;
#pragma unroll
    for (int j = 0; j < 8; ++j) z[j] = (__bf16)0.f;
    for (int i = tid; i < 2 * 4 * 64; i += 512) *(bf16x8*)&sA1[0][i * 8] = z;
    for (int i = tid; i < 2 * 2 * 64; i += 512) *(bf16x8*)&sA2[0][i * 8] = z;
  }
  __syncthreads();

  // x prefetch registers (L1 waves; lane (col,q) owns x[b0+col][t][(q&1)*8 .. +8])
  const float* xbase = x + ((size_t)(b0 + col) * T_SEQ) * 16 + (q & 1) * 8;
  float4 xcA, xcB, xnA, xnB;
  if (isL1) {
    xcA = *(const float4*)(xbase + 0);
    xcB = *(const float4*)(xbase + 4);
  }

  float c1s[4] = {0.f, 0.f, 0.f, 0.f};
  float c2s[4] = {0.f, 0.f, 0.f, 0.f};
  const int uu   = w * 16 + col;      // L1 unit
  const int uu2b = wl2b * 16 + col;   // L2b unit

  // Interval t: L1 -> h1(t) [t<T]; L2a -> pA(t-1) [1<=t<=T]; L2b -> h2(t-2) [2<=t<=T+1].
  for (int t = 0; t <= T_SEQ + 1; ++t) {
    const int p = t & 1;

    if (isL1) {
      if (t + 1 < T_SEQ) {   // issue next-x loads early
        const float* xr = xbase + (size_t)(t + 1) * 16;
        xnA = *(const float4*)(xr + 0);
        xnB = *(const float4*)(xr + 4);
      }
      if (t < T_SEQ) {
        const float xc[8] = {xcA.x, xcA.y, xcA.z, xcA.w, xcB.x, xcB.y, xcB.z, xcB.w};
        bf16x8 xh8, xl8;
#pragma unroll
        for (int j = 0; j < 8; ++j) {
          __bf16 h, l; split_bf16(xc[j], h, l);
          xh8[j] = h; xl8[j] = l;
        }
        const bf16x8 ax0 = (q < 2) ? xh8 : xl8;
        const bf16x8 ax1 = (q < 2) ? xl8 : xh8;

        bf16x8 a1[4];
#pragma unroll
        for (int kb = 0; kb < 4; ++kb) a1[kb] = *(const bf16x8*)&sA1[p][(kb * 64 + lane) * 8];

        f32x4 c[4];
#pragma unroll
        for (int g = 0; g < 4; ++g) { c[g][0] = b1v[g]; c[g][1] = b1v[g]; c[g][2] = b1v[g]; c[g][3] = b1v[g]; }
#pragma unroll
        for (int g = 0; g < 4; ++g) {
          c[g] = MFMA(ax0,   bih[g],    c[g]);
          c[g] = MFMA(ax1,   bih[g],    c[g]);
          c[g] = MFMA(a1[0], bhh[g][0], c[g]);  // hi x hi
          c[g] = MFMA(a1[1], bhh[g][1], c[g]);
          c[g] = MFMA(a1[2], bhh[g][0], c[g]);  // lo x hi
          c[g] = MFMA(a1[3], bhh[g][1], c[g]);
          c[g] = MFMA(a1[0], bhh[g][2], c[g]);  // hi x lo
          c[g] = MFMA(a1[1], bhh[g][3], c[g]);
        }
        const int kbh = uu >> 5;
        const int lnb = ((uu & 31) >> 3) * 16;
        const int jj  = uu & 7;
#pragma unroll
        for (int r = 0; r < 4; ++r) {
          const float iv = fsig(c[0][r]);
          const float fv = fsig(c[1][r]);
          const float gv = ftanhf(c[2][r]);
          const float ov = fsig(c[3][r]);
          const float cc = fmaf(fv, c1s[r], iv * gv);
          c1s[r] = cc;
          __bf16 hh, hl;
          split_bf16(ov * ftanhf(cc), hh, hl);
          const int m = q * 4 + r;
          sA1[1 - p][((kbh * 64) + lnb + m) * 8 + jj]       = hh;
          sA1[1 - p][(((2 + kbh) * 64) + lnb + m) * 8 + jj] = hl;
        }
        xcA = xnA; xcB = xnB;   // rotate prefetch
      }
    }

    if (isL2a && t >= 1 && t <= T_SEQ) {   // pA(t-1) = full W_ih2 . h1(t-1)
      bf16x8 a2[4];
#pragma unroll
      for (int kb = 0; kb < 4; ++kb) a2[kb] = *(const bf16x8*)&sA1[p][(kb * 64 + lane) * 8];
#pragma unroll
      for (int g = 0; g < 4; ++g) {
        const int nt = g * 2 + wl2a;
        const bf16x8 bb0 = *(const bf16x8*)&sW2[((nt * 4 + 0) * 64 + lane) * 8];
        const bf16x8 bb1 = *(const bf16x8*)&sW2[((nt * 4 + 1) * 64 + lane) * 8];
        const bf16x8 bb2 = *(const bf16x8*)&sW2[((nt * 4 + 2) * 64 + lane) * 8];
        const bf16x8 bb3 = *(const bf16x8*)&sW2[((nt * 4 + 3) * 64 + lane) * 8];
        f32x4 pa = {0.f, 0.f, 0.f, 0.f};
        pa = MFMA(a2[0], bb0, pa);   // hi x hi
        pa = MFMA(a2[1], bb1, pa);
        pa = MFMA(a2[0], bb2, pa);   // hi x lo
        pa = MFMA(a2[1], bb3, pa);
        pa = MFMA(a2[2], bb0, pa);   // lo x hi
        pa = MFMA(a2[3], bb1, pa);
        *(f32x4*)&sP[p][((wl2a * 4 + g) * 64 + lane) * 4] = pa;
      }
    }

    if (isL2b && t >= 2) {   // h2(t-2) = act(pA(t-2) + W_hh2 . h2(t-3))
      const bf16x8 ah0 = *(const bf16x8*)&sA2[1 - p][(0 * 64 + lane) * 8];
      const bf16x8 ah1 = *(const bf16x8*)&sA2[1 - p][(1 * 64 + lane) * 8];
      f32x4 c2[4];
#pragma unroll
      for (int g = 0; g < 4; ++g) {
        const bf16x8 whh = *(const bf16x8*)&sWh2[(((wl2b * 4 + g) * 2 + 0) * 64 + lane) * 8];
        const bf16x8 whl = *(const bf16x8*)&sWh2[(((wl2b * 4 + g) * 2 + 1) * 64 + lane) * 8];
        c2[g][0] = b2v[g]; c2[g][1] = b2v[g]; c2[g][2] = b2v[g]; c2[g][3] = b2v[g];
        c2[g] = MFMA(ah0, whh, c2[g]);   // h2hi x Whh2hi
        c2[g] = MFMA(ah1, whh, c2[g]);   // h2lo x Whh2hi
        c2[g] = MFMA(ah0, whl, c2[g]);   // h2hi x Whh2lo
        c2[g] += *(const f32x4*)&sP[1 - p][((wl2b * 4 + g) * 64 + lane) * 4];
      }
      const int lnb2 = ((uu2b & 31) >> 3) * 16;
      const int jj2  = uu2b & 7;
#pragma unroll
      for (int r = 0; r < 4; ++r) {
        const float iv = fsig(c2[0][r]);
        const float fv = fsig(c2[1][r]);
        const float gv = ftanhf(c2[2][r]);
        const float ov = fsig(c2[3][r]);
        const float cc = fmaf(fv, c2s[r], iv * gv);
        c2s[r] = cc;
        const float hf = ov * ftanhf(cc);
        __bf16 hh, hl;
        split_bf16(hf, hh, hl);
        const int m = q * 4 + r;
        sA2[p][((0 * 64) + lnb2 + m) * 8 + jj2] = hh;
        sA2[p][((1 * 64) + lnb2 + m) * 8 + jj2] = hl;
        if (t == T_SEQ + 1) sH2f[m * 32 + uu2b] = hf;
      }
    }

    __syncthreads();   // single barrier: every cross-wave dependency crosses exactly one
  }

  // ======== FC epilogue ========
  if (tid < NB) {
    float s = bfc[0];
#pragma unroll
    for (int j = 0; j < 32; ++j) s = fmaf(Wfc[j], sH2f[tid * 32 + j], s);
    out[b0 + tid] = s;
  }
}

extern "C" void kernel_launch(void* const* d_in, const int* in_sizes, int n_in,
                              void* d_out, int out_size, void* d_ws, size_t ws_size,
                              hipStream_t stream) {
  (void)in_sizes; (void)n_in; (void)out_size; (void)d_ws; (void)ws_size;
  const float* x    = (const float*)d_in[0];
  const float* Wih1 = (const float*)d_in[1];
  const float* Whh1 = (const float*)d_in[2];
  const float* bih1 = (const float*)d_in[3];
  const float* bhh1 = (const float*)d_in[4];
  const float* Wih2 = (const float*)d_in[5];
  const float* Whh2 = (const float*)d_in[6];
  const float* bih2 = (const float*)d_in[7];
  const float* bhh2 = (const float*)d_in[8];
  const float* Wfc  = (const float*)d_in[9];
  const float* bfc  = (const float*)d_in[10];
  float* out = (float*)d_out;

  hipLaunchKernelGGL(lstm_mfma_kernel, dim3(4096 / NB), dim3(512), 0, stream,
                     x, Wih1, Whh1, bih1, bhh1, Wih2, Whh2, bih2, bhh2, Wfc, bfc, out);
}

// Round 8
// 292.641 us; speedup vs baseline: 2.0182x; 1.0003x over previous
//
#include <hip/hip_runtime.h>

// 2-layer LSTM, B=4096, T=168, D=16, H1=64, H2=32, fp32 in/out.
// R8: R7's pipelined wave specialization (1 barrier/interval) with the
// t-loop peeled + unrolled x2 so the ping-pong index p is a COMPILE-TIME
// constant -> all LDS accesses use immediate offsets (R7 spent ~40% of its
// VALU issue on runtime address arithmetic for sA1[p]/sP[p]/sA2[1-p]).
// Roles (512 thr/block, grid 256, 1 block/CU):
//   w0-3 : h1(t)   = LSTM1(h1(t-1), x(t))            [32 MFMA, lo*lo dropped]
//   w6,7 : pA(t-1) = full W_ih2 . h1(t-1)            [24 MFMA, weights in LDS]
//   w4,5 : h2(t-2) = act(pA(t-2) + W_hh2 . h2(t-3))  [12 MFMA, self-recurrent]
// mfma_f32_16x16x32_bf16 hi/lo split, lo*lo dropped (validated: absmax 6.1e-5).

typedef __bf16 bf16x8 __attribute__((ext_vector_type(8)));
typedef float  f32x4  __attribute__((ext_vector_type(4)));

constexpr int T_SEQ = 168;
constexpr int NB    = 16;

__device__ __forceinline__ float fsig(float v)  { return __builtin_amdgcn_rcpf(1.f + __expf(-v)); }
__device__ __forceinline__ float ftanhf(float v){ return 2.f * __builtin_amdgcn_rcpf(1.f + __expf(-2.f * v)) - 1.f; }

__device__ __forceinline__ void split_bf16(float x, __bf16& hi, __bf16& lo) {
  hi = (__bf16)x;
  lo = (__bf16)(x - (float)hi);
}

__device__ __forceinline__ void load_frag8(const float* __restrict__ Wrow, int k0,
                                           bf16x8& hi, bf16x8& lo) {
#pragma unroll
  for (int j = 0; j < 8; ++j) {
    float v = Wrow[k0 + j];
    __bf16 h = (__bf16)v;
    hi[j] = h;
    lo[j] = (__bf16)(v - (float)h);
  }
}

#define MFMA(a, b, c) __builtin_amdgcn_mfma_f32_16x16x32_bf16((a), (b), (c), 0, 0, 0)

__global__ __launch_bounds__(512, 1)
void lstm_mfma_kernel(const float* __restrict__ x,
    const float* __restrict__ Wih1, const float* __restrict__ Whh1,
    const float* __restrict__ bih1, const float* __restrict__ bhh1,
    const float* __restrict__ Wih2, const float* __restrict__ Whh2,
    const float* __restrict__ bih2, const float* __restrict__ bhh2,
    const float* __restrict__ Wfc,  const float* __restrict__ bfc,
    float* __restrict__ out)
{
  __shared__ __align__(16) __bf16 sA1[2][4 * 64 * 8];      // h1 hi(kb0,1)/lo(kb2,3)
  __shared__ __align__(16) __bf16 sA2[2][2 * 64 * 8];      // h2 hi(kb0)/lo(kb1)
  __shared__ __align__(16) __bf16 sW2[8 * 4 * 64 * 8];     // W_ih2 frags [nt=g*2+wl][kb][lane] (32 KB)
  __shared__ __align__(16) __bf16 sWh2[2 * 4 * 2 * 64 * 8];// W_hh2 frags [(wl*4+g)*2+hl][lane] (16 KB)
  __shared__ __align__(16) float  sP[2][2 * 4 * 64 * 4];   // pA partials, ping-pong (16 KB)
  __shared__ __align__(16) float  sH2f[16 * 32];           // final h2 [batch][unit]

  const int tid  = threadIdx.x;
  const int w    = tid >> 6;        // wave 0..7
  const int lane = tid & 63;
  const int q    = lane >> 4;
  const int col  = lane & 15;
  const int b0   = blockIdx.x * NB;

  const bool isL1  = (w < 4);
  const bool isL2b = (w == 4) || (w == 5);  // combine + hh2 + act + h2 write
  const bool isL2a = (w >= 6);              // full W_ih2 . h1 -> partials
  const int  wl2b  = w - 4;
  const int  wl2a  = w - 6;

  // ---------------- L1 weights into registers (only role with reg weights) ----------------
  bf16x8 bhh[4][4];   // W_hh1 hi(kb0,1)/lo(kb2,3)
  bf16x8 bih[4];      // W_ih1 packed [Wh;Wl]
  float  b1v[4] = {0.f, 0.f, 0.f, 0.f};
  if (isL1) {
#pragma unroll
    for (int g = 0; g < 4; ++g) {
      const int r = g * 64 + w * 16 + col;
      const float* Wr = Whh1 + r * 64;
      bf16x8 h0, l0, h1f, l1f;
      load_frag8(Wr, 0 * 32 + q * 8, h0, l0);
      load_frag8(Wr, 1 * 32 + q * 8, h1f, l1f);
      bhh[g][0] = h0; bhh[g][1] = h1f; bhh[g][2] = l0; bhh[g][3] = l1f;
      bf16x8 xh, xl;
      load_frag8(Wih1 + r * 16, (q & 1) * 8, xh, xl);
      bih[g] = (q < 2) ? xh : xl;
      b1v[g] = bih1[r] + bhh1[r];
    }
  }
  float b2v[4] = {0.f, 0.f, 0.f, 0.f};
  if (isL2b) {
#pragma unroll
    for (int g = 0; g < 4; ++g) {
      const int r = g * 32 + wl2b * 16 + col;
      b2v[g] = bih2[r] + bhh2[r];
    }
  }

  // ---------------- LDS staging: W_ih2 B-frags ----------------
  for (int idx = tid; idx < 8 * 4 * 64; idx += 512) {
    const int nt = idx >> 8;          // nt = g*2 + wl
    const int kb = (idx >> 6) & 3;
    const int ln = idx & 63;
    const int qq = ln >> 4, cc = ln & 15;
    const int g  = nt >> 1, wv = nt & 1;
    const int r  = g * 32 + wv * 16 + cc;
    const int k0 = (kb & 1) * 32 + qq * 8;
    bf16x8 hh, ll;
    load_frag8(Wih2 + r * 64, k0, hh, ll);
    *(bf16x8*)&sW2[((nt * 4 + kb) * 64 + ln) * 8] = (kb < 2) ? hh : ll;
  }
  // ---------------- LDS staging: W_hh2 B-frags ----------------
  for (int idx = tid; idx < 2 * 4 * 2 * 64; idx += 512) {
    const int ln = idx & 63;
    const int hl = (idx >> 6) & 1;
    const int g  = (idx >> 7) & 3;
    const int wl = idx >> 9;
    const int qq = ln >> 4, cc = ln & 15;
    const int r  = g * 32 + wl * 16 + cc;
    bf16x8 hh, ll;
    load_frag8(Whh2 + r * 32, qq * 8, hh, ll);
    *(bf16x8*)&sWh2[(((wl * 4 + g) * 2 + hl) * 64 + ln) * 8] = hl ? ll : hh;
  }

  // ---------------- zero state buffers (both ping-pong halves) ----------------
  {
    bf16x8 z;
#pragma unroll
    for (int j = 0; j < 8; ++j) z[j] = (__bf16)0.f;
    for (int i = tid; i < 2 * 4 * 64; i += 512) *(bf16x8*)&sA1[0][i * 8] = z;
    for (int i = tid; i < 2 * 2 * 64; i += 512) *(bf16x8*)&sA2[0][i * 8] = z;
  }
  __syncthreads();

  // x prefetch registers (L1 waves; lane (col,q) owns x[b0+col][t][(q&1)*8 .. +8])
  const float* xbase = x + ((size_t)(b0 + col) * T_SEQ) * 16 + (q & 1) * 8;
  float4 xcA, xcB, xnA, xnB;
  if (isL1) {
    xcA = *(const float4*)(xbase + 0);
    xcB = *(const float4*)(xbase + 4);
  }

  float c1s[4] = {0.f, 0.f, 0.f, 0.f};
  float c2s[4] = {0.f, 0.f, 0.f, 0.f};
  const int uu   = w * 16 + col;      // L1 unit
  const int uu2b = wl2b * 16 + col;   // L2b unit

  // hoisted write-address constants
  const int kbh  = uu >> 5;
  const int lnb  = ((uu & 31) >> 3) * 16;
  const int jj   = uu & 7;
  const int lnb2 = ((uu2b & 31) >> 3) * 16;
  const int jj2  = uu2b & 7;

// One pipeline interval. Pc (0/1) and the DO_* flags are compile-time
// literals at every expansion site -> all LDS addresses fold to immediates.
#define STEP(Pc, DO_L1, DO_XPRE, DO_L2A, DO_L2B, DO_H2F, TT) do {              \
    if ((DO_XPRE) && isL1) {                                                   \
      const float* xr = xbase + (size_t)((TT) + 1) * 16;                       \
      xnA = *(const float4*)(xr + 0);                                          \
      xnB = *(const float4*)(xr + 4);                                          \
    }                                                                          \
    if ((DO_L1) && isL1) {                                                     \
      const float xc[8] = {xcA.x, xcA.y, xcA.z, xcA.w, xcB.x, xcB.y, xcB.z, xcB.w}; \
      bf16x8 xh8, xl8;                                                         \
      _Pragma("unroll")                                                        \
      for (int j = 0; j < 8; ++j) {                                            \
        __bf16 h_, l_; split_bf16(xc[j], h_, l_);                              \
        xh8[j] = h_; xl8[j] = l_;                                              \
      }                                                                        \
      const bf16x8 ax0 = (q < 2) ? xh8 : xl8;                                  \
      const bf16x8 ax1 = (q < 2) ? xl8 : xh8;                                  \
      bf16x8 a1[4];                                                            \
      _Pragma("unroll")                                                        \
      for (int kb = 0; kb < 4; ++kb)                                           \
        a1[kb] = *(const bf16x8*)&sA1[(Pc)][(kb * 64 + lane) * 8];             \
      f32x4 c[4];                                                              \
      _Pragma("unroll")                                                        \
      for (int g = 0; g < 4; ++g) { c[g][0] = b1v[g]; c[g][1] = b1v[g]; c[g][2] = b1v[g]; c[g][3] = b1v[g]; } \
      _Pragma("unroll")                                                        \
      for (int g = 0; g < 4; ++g) {                                            \
        c[g] = MFMA(ax0,   bih[g],    c[g]);                                   \
        c[g] = MFMA(ax1,   bih[g],    c[g]);                                   \
        c[g] = MFMA(a1[0], bhh[g][0], c[g]);                                   \
        c[g] = MFMA(a1[1], bhh[g][1], c[g]);                                   \
        c[g] = MFMA(a1[2], bhh[g][0], c[g]);                                   \
        c[g] = MFMA(a1[3], bhh[g][1], c[g]);                                   \
        c[g] = MFMA(a1[0], bhh[g][2], c[g]);                                   \
        c[g] = MFMA(a1[1], bhh[g][3], c[g]);                                   \
      }                                                                        \
      _Pragma("unroll")                                                        \
      for (int r = 0; r < 4; ++r) {                                            \
        const float iv = fsig(c[0][r]);                                        \
        const float fv = fsig(c[1][r]);                                        \
        const float gv = ftanhf(c[2][r]);                                      \
        const float ov = fsig(c[3][r]);                                        \
        const float cc = fmaf(fv, c1s[r], iv * gv);                            \
        c1s[r] = cc;                                                           \
        __bf16 hh_, hl_;                                                       \
        split_bf16(ov * ftanhf(cc), hh_, hl_);                                 \
        const int m = q * 4 + r;                                               \
        sA1[1 - (Pc)][((kbh * 64) + lnb + m) * 8 + jj]       = hh_;            \
        sA1[1 - (Pc)][(((2 + kbh) * 64) + lnb + m) * 8 + jj] = hl_;            \
      }                                                                        \
      if (DO_XPRE) { xcA = xnA; xcB = xnB; }                                   \
    }                                                                          \
    if ((DO_L2A) && isL2a) {                                                   \
      bf16x8 a2[4];                                                            \
      _Pragma("unroll")                                                        \
      for (int kb = 0; kb < 4; ++kb)                                           \
        a2[kb] = *(const bf16x8*)&sA1[(Pc)][(kb * 64 + lane) * 8];             \
      _Pragma("unroll")                                                        \
      for (int g = 0; g < 4; ++g) {                                            \
        const int nt = g * 2 + wl2a;                                           \
        const bf16x8 bb0 = *(const bf16x8*)&sW2[((nt * 4 + 0) * 64 + lane) * 8]; \
        const bf16x8 bb1 = *(const bf16x8*)&sW2[((nt * 4 + 1) * 64 + lane) * 8]; \
        const bf16x8 bb2 = *(const bf16x8*)&sW2[((nt * 4 + 2) * 64 + lane) * 8]; \
        const bf16x8 bb3 = *(const bf16x8*)&sW2[((nt * 4 + 3) * 64 + lane) * 8]; \
        f32x4 pa = {0.f, 0.f, 0.f, 0.f};                                       \
        pa = MFMA(a2[0], bb0, pa);                                             \
        pa = MFMA(a2[1], bb1, pa);                                             \
        pa = MFMA(a2[0], bb2, pa);                                             \
        pa = MFMA(a2[1], bb3, pa);                                             \
        pa = MFMA(a2[2], bb0, pa);                                             \
        pa = MFMA(a2[3], bb1, pa);                                             \
        *(f32x4*)&sP[(Pc)][((wl2a * 4 + g) * 64 + lane) * 4] = pa;             \
      }                                                                        \
    }                                                                          \
    if ((DO_L2B) && isL2b) {                                                   \
      const bf16x8 ah0 = *(const bf16x8*)&sA2[1 - (Pc)][(0 * 64 + lane) * 8];  \
      const bf16x8 ah1 = *(const bf16x8*)&sA2[1 - (Pc)][(1 * 64 + lane) * 8];  \
      f32x4 c2[4];                                                             \
      _Pragma("unroll")                                                        \
      for (int g = 0; g < 4; ++g) {                                            \
        const bf16x8 whh = *(const bf16x8*)&sWh2[(((wl2b * 4 + g) * 2 + 0) * 64 + lane) * 8]; \
        const bf16x8 whl = *(const bf16x8*)&sWh2[(((wl2b * 4 + g) * 2 + 1) * 64 + lane) * 8]; \
        c2[g][0] = b2v[g]; c2[g][1] = b2v[g]; c2[g][2] = b2v[g]; c2[g][3] = b2v[g]; \
        c2[g] = MFMA(ah0, whh, c2[g]);                                         \
        c2[g] = MFMA(ah1, whh, c2[g]);                                         \
        c2[g] = MFMA(ah0, whl, c2[g]);                                         \
        c2[g] += *(const f32x4*)&sP[1 - (Pc)][((wl2b * 4 + g) * 64 + lane) * 4]; \
      }                                                                        \
      _Pragma("unroll")                                                        \
      for (int r = 0; r < 4; ++r) {                                            \
        const float iv = fsig(c2[0][r]);                                       \
        const float fv = fsig(c2[1][r]);                                       \
        const float gv = ftanhf(c2[2][r]);                                     \
        const float ov = fsig(c2[3][r]);                                       \
        const float cc = fmaf(fv, c2s[r], iv * gv);                            \
        c2s[r] = cc;                                                           \
        const float hf = ov * ftanhf(cc);                                      \
        __bf16 hh_, hl_;                                                       \
        split_bf16(hf, hh_, hl_);                                              \
        const int m = q * 4 + r;                                               \
        sA2[(Pc)][((0 * 64) + lnb2 + m) * 8 + jj2] = hh_;                      \
        sA2[(Pc)][((1 * 64) + lnb2 + m) * 8 + jj2] = hl_;                      \
        if (DO_H2F) sH2f[m * 32 + uu2b] = hf;                                  \
      }                                                                        \
    }                                                                          \
    __syncthreads();                                                           \
  } while (0)

  // -------- pipeline fill --------
  STEP(0, true,  true,  false, false, false, 0);
  STEP(1, true,  true,  true,  false, false, 1);
  // -------- steady state: t = 2..165, all roles active, no guards --------
  for (int t = 2; t < 166; t += 2) {
    STEP(0, true, true, true, true, false, t);
    STEP(1, true, true, true, true, false, t + 1);
  }
  // -------- drain --------
  STEP(0, true,  true,  true,  true,  false, 166);
  STEP(1, true,  false, true,  true,  false, 167);  // last L1 step, no x prefetch
  STEP(0, false, false, true,  true,  false, 168);  // pA(167), h2(166)
  STEP(1, false, false, false, true,  true,  169);  // h2(167) + final store
#undef STEP

  // ======== FC epilogue ========
  if (tid < NB) {
    float s = bfc[0];
#pragma unroll
    for (int j = 0; j < 32; ++j) s = fmaf(Wfc[j], sH2f[tid * 32 + j], s);
    out[b0 + tid] = s;
  }
}

extern "C" void kernel_launch(void* const* d_in, const int* in_sizes, int n_in,
                              void* d_out, int out_size, void* d_ws, size_t ws_size,
                              hipStream_t stream) {
  (void)in_sizes; (void)n_in; (void)out_size; (void)d_ws; (void)ws_size;
  const float* x    = (const float*)d_in[0];
  const float* Wih1 = (const float*)d_in[1];
  const float* Whh1 = (const float*)d_in[2];
  const float* bih1 = (const float*)d_in[3];
  const float* bhh1 = (const float*)d_in[4];
  const float* Wih2 = (const float*)d_in[5];
  const float* Whh2 = (const float*)d_in[6];
  const float* bih2 = (const float*)d_in[7];
  const float* bhh2 = (const float*)d_in[8];
  const float* Wfc  = (const float*)d_in[9];
  const float* bfc  = (const float*)d_in[10];
  float* out = (float*)d_out;

  hipLaunchKernelGGL(lstm_mfma_kernel, dim3(4096 / NB), dim3(512), 0, stream,
                     x, Wih1, Whh1, bih1, bhh1, Wih2, Whh2, bih2, bhh2, Wfc, bfc, out);
}

// Round 9
// 273.495 us; speedup vs baseline: 2.1595x; 1.0700x over previous
//
#include <hip/hip_runtime.h>

// 2-layer LSTM, B=4096, T=168, D=16, H1=64, H2=32, fp32 in/out.
// R9: R8's pipelined wave specialization (1 barrier/interval, compile-time
// ping-pong) + LDS-pipe decongestion: W_hh2 and W_ih2-hi live in L2 wave
// registers (amdgpu_waves_per_eu(2,2) forces the 256-VGPR budget that R5
// lacked); only W_ih2-lo stays in LDS. L1 MFMA chain split 2-way (ca/cb)
// to halve dependent-MFMA latency on the serial h1 path.
// Roles (512 thr/block, grid 256, 1 block/CU):
//   w0-3 : h1(t)   = LSTM1(h1(t-1), x(t))            [32 MFMA, lo*lo dropped]
//   w6,7 : pA(t-1) = full W_ih2 . h1(t-1)            [24 MFMA]
//   w4,5 : h2(t-2) = act(pA(t-2) + W_hh2 . h2(t-3))  [12 MFMA, self-recurrent]
// mfma_f32_16x16x32_bf16 hi/lo split, lo*lo dropped (validated: absmax 6.1e-5).

typedef __bf16 bf16x8 __attribute__((ext_vector_type(8)));
typedef float  f32x4  __attribute__((ext_vector_type(4)));

constexpr int T_SEQ = 168;
constexpr int NB    = 16;

__device__ __forceinline__ float fsig(float v)  { return __builtin_amdgcn_rcpf(1.f + __expf(-v)); }
__device__ __forceinline__ float ftanhf(float v){ return 2.f * __builtin_amdgcn_rcpf(1.f + __expf(-2.f * v)) - 1.f; }

__device__ __forceinline__ void split_bf16(float x, __bf16& hi, __bf16& lo) {
  hi = (__bf16)x;
  lo = (__bf16)(x - (float)hi);
}

__device__ __forceinline__ void load_frag8(const float* __restrict__ Wrow, int k0,
                                           bf16x8& hi, bf16x8& lo) {
#pragma unroll
  for (int j = 0; j < 8; ++j) {
    float v = Wrow[k0 + j];
    __bf16 h = (__bf16)v;
    hi[j] = h;
    lo[j] = (__bf16)(v - (float)h);
  }
}

#define MFMA(a, b, c) __builtin_amdgcn_mfma_f32_16x16x32_bf16((a), (b), (c), 0, 0, 0)

__global__ __launch_bounds__(512) __attribute__((amdgpu_waves_per_eu(2, 2)))
void lstm_mfma_kernel(const float* __restrict__ x,
    const float* __restrict__ Wih1, const float* __restrict__ Whh1,
    const float* __restrict__ bih1, const float* __restrict__ bhh1,
    const float* __restrict__ Wih2, const float* __restrict__ Whh2,
    const float* __restrict__ bih2, const float* __restrict__ bhh2,
    const float* __restrict__ Wfc,  const float* __restrict__ bfc,
    float* __restrict__ out)
{
  __shared__ __align__(16) __bf16 sA1[2][4 * 64 * 8];      // h1 hi(kb0,1)/lo(kb2,3) (8 KB)
  __shared__ __align__(16) __bf16 sA2[2][2 * 64 * 8];      // h2 hi(kb0)/lo(kb1) (4 KB)
  __shared__ __align__(16) __bf16 sW2lo[8 * 2 * 64 * 8];   // W_ih2 LO frags [nt=g*2+wl][kb2][lane] (16 KB)
  __shared__ __align__(16) float  sP[2][2 * 4 * 64 * 4];   // pA partials, ping-pong (16 KB)
  __shared__ __align__(16) float  sH2f[16 * 32];           // final h2 [batch][unit]

  const int tid  = threadIdx.x;
  const int w    = tid >> 6;        // wave 0..7
  const int lane = tid & 63;
  const int q    = lane >> 4;
  const int col  = lane & 15;
  const int b0   = blockIdx.x * NB;

  const bool isL1  = (w < 4);
  const bool isL2b = (w == 4) || (w == 5);  // combine + hh2 + act + h2 write
  const bool isL2a = (w >= 6);              // full W_ih2 . h1 -> partials
  const int  wl2b  = w - 4;
  const int  wl2a  = w - 6;

  // ---------------- L1 weights into registers ----------------
  bf16x8 bhh[4][4];   // W_hh1 hi(kb0,1)/lo(kb2,3)
  bf16x8 bih[4];      // W_ih1 packed [Wh;Wl]
  float  b1v[4] = {0.f, 0.f, 0.f, 0.f};
  if (isL1) {
#pragma unroll
    for (int g = 0; g < 4; ++g) {
      const int r = g * 64 + w * 16 + col;
      const float* Wr = Whh1 + r * 64;
      bf16x8 h0, l0, h1f, l1f;
      load_frag8(Wr, 0 * 32 + q * 8, h0, l0);
      load_frag8(Wr, 1 * 32 + q * 8, h1f, l1f);
      bhh[g][0] = h0; bhh[g][1] = h1f; bhh[g][2] = l0; bhh[g][3] = l1f;
      bf16x8 xh, xl;
      load_frag8(Wih1 + r * 16, (q & 1) * 8, xh, xl);
      bih[g] = (q < 2) ? xh : xl;
      b1v[g] = bih1[r] + bhh1[r];
    }
  }
  // ---------------- L2b weights into registers: W_hh2 hi/lo ----------------
  bf16x8 wh2h[4], wh2l[4];
  float  b2v[4] = {0.f, 0.f, 0.f, 0.f};
  if (isL2b) {
#pragma unroll
    for (int g = 0; g < 4; ++g) {
      const int r = g * 32 + wl2b * 16 + col;
      bf16x8 hh, ll;
      load_frag8(Whh2 + r * 32, q * 8, hh, ll);
      wh2h[g] = hh; wh2l[g] = ll;
      b2v[g] = bih2[r] + bhh2[r];
    }
  }
  // ---------------- L2a weights into registers: W_ih2 HI ----------------
  bf16x8 w2ih[4][2];
  if (isL2a) {
#pragma unroll
    for (int g = 0; g < 4; ++g) {
      const int r = g * 32 + wl2a * 16 + col;
#pragma unroll
      for (int kb = 0; kb < 2; ++kb) {
        bf16x8 hh, ll;
        load_frag8(Wih2 + r * 64, kb * 32 + q * 8, hh, ll);
        w2ih[g][kb] = hh;
      }
    }
  }

  // ---------------- LDS staging: W_ih2 LO frags only ----------------
  for (int idx = tid; idx < 8 * 2 * 64; idx += 512) {
    const int nt  = idx >> 7;         // nt = g*2 + wl
    const int kb2 = (idx >> 6) & 1;
    const int ln  = idx & 63;
    const int qq  = ln >> 4, cc = ln & 15;
    const int g   = nt >> 1, wv = nt & 1;
    const int r   = g * 32 + wv * 16 + cc;
    const int k0  = kb2 * 32 + qq * 8;
    bf16x8 hh, ll;
    load_frag8(Wih2 + r * 64, k0, hh, ll);
    *(bf16x8*)&sW2lo[((nt * 2 + kb2) * 64 + ln) * 8] = ll;
  }

  // ---------------- zero state buffers (both ping-pong halves) ----------------
  {
    bf16x8 z;
#pragma unroll
    for (int j = 0; j < 8; ++j) z[j] = (__bf16)0.f;
    for (int i = tid; i < 2 * 4 * 64; i += 512) *(bf16x8*)&sA1[0][i * 8] = z;
    for (int i = tid; i < 2 * 2 * 64; i += 512) *(bf16x8*)&sA2[0][i * 8] = z;
  }
  __syncthreads();

  // x prefetch registers (L1 waves; lane (col,q) owns x[b0+col][t][(q&1)*8 .. +8])
  const float* xbase = x + ((size_t)(b0 + col) * T_SEQ) * 16 + (q & 1) * 8;
  float4 xcA, xcB, xnA, xnB;
  if (isL1) {
    xcA = *(const float4*)(xbase + 0);
    xcB = *(const float4*)(xbase + 4);
  }

  float c1s[4] = {0.f, 0.f, 0.f, 0.f};
  float c2s[4] = {0.f, 0.f, 0.f, 0.f};
  const int uu   = w * 16 + col;      // L1 unit
  const int uu2b = wl2b * 16 + col;   // L2b unit

  // hoisted write-address constants
  const int kbh  = uu >> 5;
  const int lnb  = ((uu & 31) >> 3) * 16;
  const int jj   = uu & 7;
  const int lnb2 = ((uu2b & 31) >> 3) * 16;
  const int jj2  = uu2b & 7;

// One pipeline interval. Pc and DO_* are compile-time literals.
#define STEP(Pc, DO_L1, DO_XPRE, DO_L2A, DO_L2B, DO_H2F, TT) do {              \
    if ((DO_L1) && isL1) {                                                     \
      bf16x8 a1[4];                                                            \
      _Pragma("unroll")                                                        \
      for (int kb = 0; kb < 4; ++kb)                                           \
        a1[kb] = *(const bf16x8*)&sA1[(Pc)][(kb * 64 + lane) * 8];             \
      if (DO_XPRE) {                                                           \
        const float* xr = xbase + (size_t)((TT) + 1) * 16;                     \
        xnA = *(const float4*)(xr + 0);                                        \
        xnB = *(const float4*)(xr + 4);                                        \
      }                                                                        \
      const float xc[8] = {xcA.x, xcA.y, xcA.z, xcA.w, xcB.x, xcB.y, xcB.z, xcB.w}; \
      bf16x8 xh8, xl8;                                                         \
      _Pragma("unroll")                                                        \
      for (int j = 0; j < 8; ++j) {                                            \
        __bf16 h_, l_; split_bf16(xc[j], h_, l_);                              \
        xh8[j] = h_; xl8[j] = l_;                                              \
      }                                                                        \
      const bf16x8 ax0 = (q < 2) ? xh8 : xl8;                                  \
      const bf16x8 ax1 = (q < 2) ? xl8 : xh8;                                  \
      f32x4 ca[4], cb[4];                                                      \
      _Pragma("unroll")                                                        \
      for (int g = 0; g < 4; ++g) {                                            \
        ca[g][0] = b1v[g]; ca[g][1] = b1v[g]; ca[g][2] = b1v[g]; ca[g][3] = b1v[g]; \
        cb[g][0] = 0.f; cb[g][1] = 0.f; cb[g][2] = 0.f; cb[g][3] = 0.f;        \
      }                                                                        \
      _Pragma("unroll")                                                        \
      for (int g = 0; g < 4; ++g) {                                            \
        ca[g] = MFMA(ax0,   bih[g],    ca[g]);                                 \
        ca[g] = MFMA(ax1,   bih[g],    ca[g]);                                 \
        ca[g] = MFMA(a1[0], bhh[g][0], ca[g]);                                 \
        ca[g] = MFMA(a1[1], bhh[g][1], ca[g]);                                 \
        cb[g] = MFMA(a1[2], bhh[g][0], cb[g]);                                 \
        cb[g] = MFMA(a1[3], bhh[g][1], cb[g]);                                 \
        cb[g] = MFMA(a1[0], bhh[g][2], cb[g]);                                 \
        cb[g] = MFMA(a1[1], bhh[g][3], cb[g]);                                 \
      }                                                                        \
      _Pragma("unroll")                                                        \
      for (int r = 0; r < 4; ++r) {                                            \
        const float iv = fsig(ca[0][r] + cb[0][r]);                            \
        const float fv = fsig(ca[1][r] + cb[1][r]);                            \
        const float gv = ftanhf(ca[2][r] + cb[2][r]);                          \
        const float ov = fsig(ca[3][r] + cb[3][r]);                            \
        const float cc = fmaf(fv, c1s[r], iv * gv);                            \
        c1s[r] = cc;                                                           \
        __bf16 hh_, hl_;                                                       \
        split_bf16(ov * ftanhf(cc), hh_, hl_);                                 \
        const int m = q * 4 + r;                                               \
        sA1[1 - (Pc)][((kbh * 64) + lnb + m) * 8 + jj]       = hh_;            \
        sA1[1 - (Pc)][(((2 + kbh) * 64) + lnb + m) * 8 + jj] = hl_;            \
      }                                                                        \
      if (DO_XPRE) { xcA = xnA; xcB = xnB; }                                   \
    }                                                                          \
    if ((DO_L2A) && isL2a) {                                                   \
      bf16x8 a2[4];                                                            \
      _Pragma("unroll")                                                        \
      for (int kb = 0; kb < 4; ++kb)                                           \
        a2[kb] = *(const bf16x8*)&sA1[(Pc)][(kb * 64 + lane) * 8];             \
      _Pragma("unroll")                                                        \
      for (int g = 0; g < 4; ++g) {                                            \
        const int nt = g * 2 + wl2a;                                           \
        const bf16x8 bb2 = *(const bf16x8*)&sW2lo[((nt * 2 + 0) * 64 + lane) * 8]; \
        const bf16x8 bb3 = *(const bf16x8*)&sW2lo[((nt * 2 + 1) * 64 + lane) * 8]; \
        f32x4 pa = {0.f, 0.f, 0.f, 0.f};                                       \
        pa = MFMA(a2[0], w2ih[g][0], pa);   /* hi x hi */                      \
        pa = MFMA(a2[1], w2ih[g][1], pa);                                      \
        pa = MFMA(a2[0], bb2, pa);          /* hi x lo */                      \
        pa = MFMA(a2[1], bb3, pa);                                             \
        pa = MFMA(a2[2], w2ih[g][0], pa);   /* lo x hi */                      \
        pa = MFMA(a2[3], w2ih[g][1], pa);                                      \
        *(f32x4*)&sP[(Pc)][((wl2a * 4 + g) * 64 + lane) * 4] = pa;             \
      }                                                                        \
    }                                                                          \
    if ((DO_L2B) && isL2b) {                                                   \
      const bf16x8 ah0 = *(const bf16x8*)&sA2[1 - (Pc)][(0 * 64 + lane) * 8];  \
      const bf16x8 ah1 = *(const bf16x8*)&sA2[1 - (Pc)][(1 * 64 + lane) * 8];  \
      f32x4 c2[4];                                                             \
      _Pragma("unroll")                                                        \
      for (int g = 0; g < 4; ++g) {                                            \
        c2[g][0] = b2v[g]; c2[g][1] = b2v[g]; c2[g][2] = b2v[g]; c2[g][3] = b2v[g]; \
        c2[g] = MFMA(ah0, wh2h[g], c2[g]);                                     \
        c2[g] = MFMA(ah1, wh2h[g], c2[g]);                                     \
        c2[g] = MFMA(ah0, wh2l[g], c2[g]);                                     \
        c2[g] += *(const f32x4*)&sP[1 - (Pc)][((wl2b * 4 + g) * 64 + lane) * 4]; \
      }                                                                        \
      _Pragma("unroll")                                                        \
      for (int r = 0; r < 4; ++r) {                                            \
        const float iv = fsig(c2[0][r]);                                       \
        const float fv = fsig(c2[1][r]);                                       \
        const float gv = ftanhf(c2[2][r]);                                     \
        const float ov = fsig(c2[3][r]);                                       \
        const float cc = fmaf(fv, c2s[r], iv * gv);                            \
        c2s[r] = cc;                                                           \
        const float hf = ov * ftanhf(cc);                                      \
        __bf16 hh_, hl_;                                                       \
        split_bf16(hf, hh_, hl_);                                              \
        const int m = q * 4 + r;                                               \
        sA2[(Pc)][((0 * 64) + lnb2 + m) * 8 + jj2] = hh_;                      \
        sA2[(Pc)][((1 * 64) + lnb2 + m) * 8 + jj2] = hl_;                      \
        if (DO_H2F) sH2f[m * 32 + uu2b] = hf;                                  \
      }                                                                        \
    }                                                                          \
    __syncthreads();                                                           \
  } while (0)

  // -------- pipeline fill --------
  STEP(0, true,  true,  false, false, false, 0);
  STEP(1, true,  true,  true,  false, false, 1);
  // -------- steady state --------
  for (int t = 2; t < 166; t += 2) {
    STEP(0, true, true, true, true, false, t);
    STEP(1, true, true, true, true, false, t + 1);
  }
  // -------- drain --------
  STEP(0, true,  true,  true,  true,  false, 166);
  STEP(1, true,  false, true,  true,  false, 167);
  STEP(0, false, false, true,  true,  false, 168);
  STEP(1, false, false, false, true,  true,  169);
#undef STEP

  // ======== FC epilogue ========
  if (tid < NB) {
    float s = bfc[0];
#pragma unroll
    for (int j = 0; j < 32; ++j) s = fmaf(Wfc[j], sH2f[tid * 32 + j], s);
    out[b0 + tid] = s;
  }
}

extern "C" void kernel_launch(void* const* d_in, const int* in_sizes, int n_in,
                              void* d_out, int out_size, void* d_ws, size_t ws_size,
                              hipStream_t stream) {
  (void)in_sizes; (void)n_in; (void)out_size; (void)d_ws; (void)ws_size;
  const float* x    = (const float*)d_in[0];
  const float* Wih1 = (const float*)d_in[1];
  const float* Whh1 = (const float*)d_in[2];
  const float* bih1 = (const float*)d_in[3];
  const float* bhh1 = (const float*)d_in[4];
  const float* Wih2 = (const float*)d_in[5];
  const float* Whh2 = (const float*)d_in[6];
  const float* bih2 = (const float*)d_in[7];
  const float* bhh2 = (const float*)d_in[8];
  const float* Wfc  = (const float*)d_in[9];
  const float* bfc  = (const float*)d_in[10];
  float* out = (float*)d_out;

  hipLaunchKernelGGL(lstm_mfma_kernel, dim3(4096 / NB), dim3(512), 0, stream,
                     x, Wih1, Whh1, bih1, bhh1, Wih2, Whh2, bih2, bhh2, Wfc, bfc, out);
}